// Round 4
// baseline (106.712 us; speedup 1.0000x reference)
//
#include <hip/hip_runtime.h>
#include <math.h>

#define NCH 64

typedef __bf16 bf16x8 __attribute__((ext_vector_type(8)));
typedef float f32x4 __attribute__((ext_vector_type(4)));

__global__ void ab_zero(float* __restrict__ ws) {
    int i = blockIdx.x * blockDim.x + threadIdx.x;
    if (i < NCH * 10) ws[i] = 0.0f;
}

// Main: per 16-neighbor tile per wave:
//   h2 = h @ W.T via mfma_f32_16x16x32_bf16 (M=16 nbrs, N=64 ch, K=64)
//   epilogue: radial(n,r) * h2 * monomials -> D[k][10] per-lane accumulators
// Occupancy build: B-fragments live in LDS (re-read per tile, LICM-blocked),
// depth-1 h prefetch only -> VGPR <= 128 -> 4 waves/SIMD.
__global__ __launch_bounds__(256, 4) void ab_main(
    const float* __restrict__ h, const float* __restrict__ rp,
    const float* __restrict__ W, float* __restrict__ ws, int N)
{
    const int lane = threadIdx.x & 63;
    const int wid  = threadIdx.x >> 6;
    const int c = lane & 15;   // A row / C col (k within 16-tile)
    const int g = lane >> 4;   // k-slot group
    const int gwave = blockIdx.x * 4 + wid;
    const int nwave = gridDim.x * 4;

    // B fragments -> LDS [frag][lane], frag = t*2+jb (16B per lane per frag)
    __shared__ bf16x8 BfL[8][64];
    if (wid == 0) {
#pragma unroll
        for (int t = 0; t < 4; ++t)
#pragma unroll
          for (int jb = 0; jb < 2; ++jb) {
            const float* wp = W + (t * 16 + c) * NCH + jb * 32 + g * 8;
            f32x4 w0 = *(const f32x4*)wp;
            f32x4 w1 = *(const f32x4*)(wp + 4);
            bf16x8 f;
#pragma unroll
            for (int e = 0; e < 4; ++e) { f[e] = (__bf16)w0[e]; f[4 + e] = (__bf16)w1[e]; }
            BfL[t * 2 + jb][lane] = f;
          }
    }
    __syncthreads();

    float D[4][10];
#pragma unroll
    for (int t = 0; t < 4; ++t)
#pragma unroll
      for (int p = 0; p < 10; ++p) D[t][p] = 0.0f;

    const float C0 = 0.632455532033676f; // sqrt(2/5)
    const float cf1 = (float)(c + 1);
    const int numTiles = N >> 4;         // N % 16 == 0 for this problem
    const unsigned bfoff = (unsigned)(lane * (int)sizeof(bf16x8));

    // depth-1 register prefetch of the h tile (4 x 16B per lane)
    f32x4 A00, A10, A01, A11;
    auto issueH = [&](int tile) {
        const float* hp = h + (size_t)((tile << 4) + c) * NCH + g * 8;
        A00 = *(const f32x4*)(hp);
        A10 = *(const f32x4*)(hp + 4);
        A01 = *(const f32x4*)(hp + 32);
        A11 = *(const f32x4*)(hp + 36);
    };

    if (gwave < numTiles) issueH(gwave);

    for (int tile = gwave; tile < numTiles; tile += nwave) {
        f32x4 a00 = A00, a10 = A10, a01 = A01, a11 = A11;
        const int nt = tile + nwave;
        issueH(nt < numTiles ? nt : gwave);  // clamp: valid addr, result discarded

        // rp loads (un-prefetched; issued early, consumed in epilogue)
        const int a0i = (tile << 4) + g * 4;
        f32x4 px = *(const f32x4*)(rp + a0i);
        f32x4 py = *(const f32x4*)(rp + N + a0i);
        f32x4 pz = *(const f32x4*)(rp + 2 * N + a0i);

        bf16x8 Af[2];
#pragma unroll
        for (int e = 0; e < 4; ++e) {
            Af[0][e] = (__bf16)a00[e]; Af[0][4 + e] = (__bf16)a10[e];
            Af[1][e] = (__bf16)a01[e]; Af[1][4 + e] = (__bf16)a11[e];
        }

        // opaque per-iteration offset: blocks LICM from hoisting the 8 frag
        // reads out of the loop (which would re-spend 32 VGPRs)
        unsigned bo = bfoff;
        asm volatile("" : "+v"(bo));
        const char* lb = (const char*)BfL + bo;

        f32x4 acc[4];
#pragma unroll
        for (int t = 0; t < 4; ++t) acc[t] = (f32x4){0.f, 0.f, 0.f, 0.f};
#pragma unroll
        for (int jb = 0; jb < 2; ++jb)
#pragma unroll
          for (int t = 0; t < 4; ++t) {
            bf16x8 bf = *(const bf16x8*)(lb + (t * 2 + jb) * 64 * sizeof(bf16x8));
            acc[t] = __builtin_amdgcn_mfma_f32_16x16x32_bf16(Af[jb], bf, acc[t], 0, 0, 0);
          }

        // C layout: lane holds rows (neighbors) g*4+i, col k = 16*t + c
#pragma unroll
        for (int i = 0; i < 4; ++i) {
            float x = px[i], y = py[i], z = pz[i];
            float r2 = x * x + y * y + z * z;
            float inv = rsqrtf(r2);
            float nx = x * inv, ny = y * inv, nz = z * inv;
            float rev1 = (r2 * inv) * 0.1f;   // r/10 revolutions per unit n
            float coef = C0 * inv;            // sqrt(2/5)/r
            float xx = nx * nx, xy = nx * ny, xz = nx * nz;
            float yy = ny * ny, yz = ny * nz, zz = nz * nz;
            float m[10] = { xx * nx, xx * ny, xx * nz, xy * ny, xy * nz,
                            xz * nz, yy * ny, yy * nz, yz * nz, zz * nz };
            float revn = cf1 * rev1;
            float rev16 = 16.0f * rev1;
#pragma unroll
            for (int t = 0; t < 4; ++t) {
                float rv = revn - floorf(revn);
                float s = __builtin_amdgcn_sinf(rv);     // sin(2*pi*rv)
                float v = s * coef * acc[t][i];
#pragma unroll
                for (int p = 0; p < 10; ++p) D[t][p] = fmaf(v, m[p], D[t][p]);
                revn += rev16;
            }
        }
    }

    // wave reduce across the 4 groups (same k set, different neighbors)
#pragma unroll
    for (int t = 0; t < 4; ++t)
#pragma unroll
      for (int p = 0; p < 10; ++p) {
        float v = D[t][p];
        v += __shfl_xor(v, 16);
        v += __shfl_xor(v, 32);
        D[t][p] = v;
      }

    __shared__ float Ds[4][NCH * 10];
    if (lane < 16) {
#pragma unroll
        for (int t = 0; t < 4; ++t)
#pragma unroll
          for (int p = 0; p < 10; ++p)
            Ds[wid][(c + 16 * t) * 10 + p] = D[t][p];
    }
    __syncthreads();
    for (int idx = threadIdx.x; idx < NCH * 10; idx += blockDim.x) {
        float s = Ds[0][idx] + Ds[1][idx] + Ds[2][idx] + Ds[3][idx];
        atomicAdd(&ws[idx], s);
    }
}

// expand 10 symmetric monomials -> 27-entry (x,y,z) tensor per channel
__global__ void ab_expand(const float* __restrict__ ws, float* __restrict__ out) {
    const unsigned char tab[27] = { 0,1,2, 1,3,4, 2,4,5,
                                    1,3,4, 3,6,7, 4,7,8,
                                    2,4,5, 4,7,8, 5,8,9 };
    int i = blockIdx.x * blockDim.x + threadIdx.x;
    if (i < NCH * 27) {
        int k = i / 27, cc = i % 27;
        out[i] = ws[k * 10 + tab[cc]];
    }
}

extern "C" void kernel_launch(void* const* d_in, const int* in_sizes, int n_in,
                              void* d_out, int out_size, void* d_ws, size_t ws_size,
                              hipStream_t stream) {
    const float* h  = (const float*)d_in[0];
    const float* rp = (const float*)d_in[1];
    const float* W  = (const float*)d_in[2];
    float* out = (float*)d_out;
    float* ws  = (float*)d_ws;
    const int N = in_sizes[1] / 3;

    ab_zero<<<1, 640, 0, stream>>>(ws);
    ab_main<<<1024, 256, 0, stream>>>(h, rp, W, ws, N);
    ab_expand<<<(NCH * 27 + 255) / 256, 256, 0, stream>>>(ws, out);
}

// Round 5
// 60.433 us; speedup vs baseline: 1.7658x; 1.7658x over previous
//
#include <hip/hip_runtime.h>
#include <math.h>

#define NCH 64

typedef __bf16 bf16x8 __attribute__((ext_vector_type(8)));
typedef float f32x4 __attribute__((ext_vector_type(4)));

__global__ void ab_zero(float* __restrict__ ws) {
    int i = blockIdx.x * blockDim.x + threadIdx.x;
    if (i < NCH * 10) ws[i] = 0.0f;
}

__device__ __forceinline__ void glds16(const void* g, void* l) {
    __builtin_amdgcn_global_load_lds(
        (const __attribute__((address_space(1))) void*)g,
        (__attribute__((address_space(3))) void*)l, 16, 0, 0);
}

// Per 16-neighbor tile per wave:
//   stage h-tile (4KB) via 4 dense global_load_lds_dwordx4 into per-wave LDS
//   (double-buffered, XOR-swizzled via pre-swizzled global source),
//   h2 = h @ W.T via mfma_f32_16x16x32_bf16 (M=16 nbrs, N=64 ch, K=64),
//   epilogue: v[k,a] = radial(k,r_a)*h2[a,k]; D[k,p] += v·M via a second
//   K=32-padded mfma (A-row=k-channel, B-col=monomial p, k-slots=neighbors).
__global__ __launch_bounds__(256, 2) void ab_main(
    const float* __restrict__ h, const float* __restrict__ rp,
    const float* __restrict__ W, float* __restrict__ ws, int N)
{
    const int lane = threadIdx.x & 63;
    const int wid  = threadIdx.x >> 6;
    const int c = lane & 15;   // MFMA row/col within 16
    const int g = lane >> 4;   // k-slot group
    const int gwave = blockIdx.x * 4 + wid;
    const int nwave = gridDim.x * 4;

    __shared__ char  ldsb[4][2][4096];   // per-wave double-buffered h tile
    __shared__ float Ds[4][NCH * 10];

    // W fragments in registers (loop-invariant): B[j,k]=W[k][j]
    bf16x8 Bf[4][2];
#pragma unroll
    for (int t = 0; t < 4; ++t)
#pragma unroll
      for (int jb = 0; jb < 2; ++jb) {
        const float* wp = W + (t * 16 + c) * NCH + jb * 32 + g * 8;
        f32x4 w0 = *(const f32x4*)wp;
        f32x4 w1 = *(const f32x4*)(wp + 4);
#pragma unroll
        for (int e = 0; e < 4; ++e) { Bf[t][jb][e] = (__bf16)w0[e]; Bf[t][jb][4 + e] = (__bf16)w1[e]; }
      }

    // swizzled LDS read offsets (loop-invariant): a = c*256+g*32+{0,16,128,144}
    int offr[4];
    {
        int a0 = c * 256 + g * 32;
        int xr = (c & 7) << 4;
        offr[0] = (a0 + 0)   ^ xr;
        offr[1] = (a0 + 16)  ^ xr;
        offr[2] = (a0 + 128) ^ xr;
        offr[3] = (a0 + 144) ^ xr;
    }
    // pre-swizzled global source offsets for staging (involution of the above)
    int offs[4];
#pragma unroll
    for (int k = 0; k < 4; ++k) {
        int lin = k * 1024 + lane * 16;
        int row = lin >> 8;
        offs[k] = lin ^ ((row & 7) << 4);
    }

    // monomial exponent selectors for this lane's output column p = c
    // p list: xxx,xxy,xxz,xyy,xyz,xzz,yyy,yyz,yzz,zzz
    const int cp = (c < 10) ? c : 9;
    const int E1[10] = {0,0,0,0,0,0,1,1,1,2};
    const int E2[10] = {0,0,0,1,1,2,1,1,2,2};
    const int E3[10] = {0,1,2,1,2,2,1,2,2,2};
    const int e1 = E1[cp], e2 = E2[cp], e3 = E3[cp];

    f32x4 d2[4];
#pragma unroll
    for (int t = 0; t < 4; ++t) d2[t] = (f32x4){0.f, 0.f, 0.f, 0.f};

    const float C0 = 0.632455532033676f; // sqrt(2/5)
    const float cf1 = (float)(c + 1);
    const int numTiles = N >> 4;         // N % 16 == 0

    f32x4 Prx, Pry, Prz;
    auto stage = [&](char* dst, int tile) {
        const char* gb = (const char*)h + (size_t)tile * 4096;
#pragma unroll
        for (int k = 0; k < 4; ++k) glds16(gb + offs[k], dst + k * 1024);
    };
    auto rpload = [&](int tile) {
        const int ai = (tile << 4) + g * 4;
        Prx = *(const f32x4*)(rp + ai);
        Pry = *(const f32x4*)(rp + N + ai);
        Prz = *(const f32x4*)(rp + 2 * N + ai);
    };

    int pbuf = 0;
    if (gwave < numTiles) { stage(&ldsb[wid][0][0], gwave); rpload(gwave); }

    for (int tile = gwave; tile < numTiles; tile += nwave) {
        char* cur = &ldsb[wid][pbuf][0];
        char* nxt = &ldsb[wid][pbuf ^ 1][0];

        // fragments from LDS (compiler inserts the vmcnt wait for cur's glds)
        f32x4 h00 = *(const f32x4*)(cur + offr[0]);
        f32x4 h01 = *(const f32x4*)(cur + offr[1]);
        f32x4 h10 = *(const f32x4*)(cur + offr[2]);
        f32x4 h11 = *(const f32x4*)(cur + offr[3]);
        f32x4 px = Prx, py = Pry, pz = Prz;

        // stage next tile (overlaps with the ~600cy compute below)
        const int nt = tile + nwave;
        const int st = (nt < numTiles) ? nt : gwave;  // clamp: valid, discarded
        stage(nxt, st);
        rpload(st);

        bf16x8 Af[2];
#pragma unroll
        for (int e = 0; e < 4; ++e) {
            Af[0][e] = (__bf16)h00[e]; Af[0][4 + e] = (__bf16)h01[e];
            Af[1][e] = (__bf16)h10[e]; Af[1][4 + e] = (__bf16)h11[e];
        }

        f32x4 acc[4];
#pragma unroll
        for (int t = 0; t < 4; ++t) acc[t] = (f32x4){0.f, 0.f, 0.f, 0.f};
#pragma unroll
        for (int jb = 0; jb < 2; ++jb)
#pragma unroll
          for (int t = 0; t < 4; ++t)
            acc[t] = __builtin_amdgcn_mfma_f32_16x16x32_bf16(Af[jb], Bf[t][jb], acc[t], 0, 0, 0);

        // epilogue: radial factors + one monomial per lane
        float vm[4][4];   // [t][i] = sin(n=16t+c+1, r_i) * coef_i
        bf16x8 B2;
#pragma unroll
        for (int e = 4; e < 8; ++e) B2[e] = (__bf16)0.0f;
#pragma unroll
        for (int i = 0; i < 4; ++i) {
            float x = px[i], y = py[i], z = pz[i];
            float r2 = x * x + y * y + z * z;
            float inv = rsqrtf(r2);
            float nx = x * inv, ny = y * inv, nz = z * inv;
            float rev1 = (r2 * inv) * 0.1f;   // r/10 revolutions per unit n
            float coef = C0 * inv;            // sqrt(2/5)/r
            float s1 = (e1 == 0) ? nx : ((e1 == 1) ? ny : nz);
            float s2 = (e2 == 0) ? nx : ((e2 == 1) ? ny : nz);
            float s3 = (e3 == 0) ? nx : ((e3 == 1) ? ny : nz);
            B2[i] = (__bf16)(s1 * s2 * s3);
            float revn = cf1 * rev1;
            float rev16 = 16.0f * rev1;
#pragma unroll
            for (int t = 0; t < 4; ++t) {
                float rv = revn - floorf(revn);
                vm[t][i] = __builtin_amdgcn_sinf(rv) * coef;
                revn += rev16;
            }
        }
#pragma unroll
        for (int t = 0; t < 4; ++t) {
            bf16x8 A2;
#pragma unroll
            for (int i = 0; i < 4; ++i) A2[i] = (__bf16)(vm[t][i] * acc[t][i]);
#pragma unroll
            for (int e = 4; e < 8; ++e) A2[e] = (__bf16)0.0f;
            d2[t] = __builtin_amdgcn_mfma_f32_16x16x32_bf16(A2, B2, d2[t], 0, 0, 0);
        }
        pbuf ^= 1;
    }

    // D2 layout: lane (c,g) holds D[k=16t+g*4+reg][p=c] for c<10
    if (c < 10) {
#pragma unroll
        for (int t = 0; t < 4; ++t)
#pragma unroll
          for (int r = 0; r < 4; ++r)
            Ds[wid][(16 * t + g * 4 + r) * 10 + c] = d2[t][r];
    }
    __syncthreads();
    for (int idx = threadIdx.x; idx < NCH * 10; idx += blockDim.x) {
        float s = Ds[0][idx] + Ds[1][idx] + Ds[2][idx] + Ds[3][idx];
        atomicAdd(&ws[idx], s);
    }
}

// expand 10 symmetric monomials -> 27-entry (x,y,z) tensor per channel
__global__ void ab_expand(const float* __restrict__ ws, float* __restrict__ out) {
    const unsigned char tab[27] = { 0,1,2, 1,3,4, 2,4,5,
                                    1,3,4, 3,6,7, 4,7,8,
                                    2,4,5, 4,7,8, 5,8,9 };
    int i = blockIdx.x * blockDim.x + threadIdx.x;
    if (i < NCH * 27) {
        int k = i / 27, cc = i % 27;
        out[i] = ws[k * 10 + tab[cc]];
    }
}

extern "C" void kernel_launch(void* const* d_in, const int* in_sizes, int n_in,
                              void* d_out, int out_size, void* d_ws, size_t ws_size,
                              hipStream_t stream) {
    const float* h  = (const float*)d_in[0];
    const float* rp = (const float*)d_in[1];
    const float* W  = (const float*)d_in[2];
    float* out = (float*)d_out;
    float* ws  = (float*)d_ws;
    const int N = in_sizes[1] / 3;

    ab_zero<<<1, 640, 0, stream>>>(ws);
    ab_main<<<512, 256, 0, stream>>>(h, rp, W, ws, N);
    ab_expand<<<(NCH * 27 + 255) / 256, 256, 0, stream>>>(ws, out);
}